// Round 1
// baseline (3711.018 us; speedup 1.0000x reference)
//
#include <hip/hip_runtime.h>
#include <hip/hip_bf16.h>
#include <cstddef>

// Problem constants
#define BB   32      // batch
#define TT   2048    // time steps
#define DIN  512     // input dim
#define DD   512     // hidden dim
#define NN   3072    // 6*DD
// GEMM tile config
#define BM 128
#define BN 128
#define BK 16

// ---------------------------------------------------------------------------
// Phase 1: proj[tl*B + b][o] = dot(x[b][t0+tl][:], W[o][:]) + bias[o]
// f32 tiled GEMM, 256 threads, 8x8 micro-tile per thread.
// Rows r (chunk-local) map to (t = t0 + r/B, b = r%B).
// ---------------------------------------------------------------------------
__global__ __launch_bounds__(256) void gemm_proj(
    const float* __restrict__ x,    // [B, T, DIN]
    const float* __restrict__ W,    // [NN, DIN]
    const float* __restrict__ bias, // [NN]
    float* __restrict__ proj,       // [Mc, NN] chunk-local
    int t0)
{
    __shared__ float As[BK][BM];
    __shared__ float Bs[BK][BN];

    const int tid  = threadIdx.x;
    const int tx   = tid & 15;       // 0..15 (cols)
    const int ty   = tid >> 4;       // 0..15 (rows)
    const int row0 = blockIdx.y * BM;
    const int col0 = blockIdx.x * BN;

    float acc[8][8];
    #pragma unroll
    for (int i = 0; i < 8; ++i)
        #pragma unroll
        for (int j = 0; j < 8; ++j) acc[i][j] = 0.f;

    for (int k0 = 0; k0 < DIN; k0 += BK) {
        // Stage A tile (x rows): 128x16 floats
        #pragma unroll
        for (int l = 0; l < 2; ++l) {
            int idx = (tid + l * 256) * 4;      // 0..4092 step 4
            int r   = idx >> 4;                 // /BK
            int c   = idx & 15;                 // %BK (0,4,8,12)
            int gr  = row0 + r;
            int t   = t0 + (gr >> 5);           // gr / B
            int bb  = gr & 31;                  // gr % B
            const float4 v = *(const float4*)(x + ((size_t)bb * TT + t) * DIN + k0 + c);
            As[c + 0][r] = v.x;
            As[c + 1][r] = v.y;
            As[c + 2][r] = v.z;
            As[c + 3][r] = v.w;
        }
        // Stage B tile (W rows): 128x16 floats
        #pragma unroll
        for (int l = 0; l < 2; ++l) {
            int idx = (tid + l * 256) * 4;
            int r   = idx >> 4;
            int c   = idx & 15;
            int go  = col0 + r;
            const float4 v = *(const float4*)(W + (size_t)go * DIN + k0 + c);
            Bs[c + 0][r] = v.x;
            Bs[c + 1][r] = v.y;
            Bs[c + 2][r] = v.z;
            Bs[c + 3][r] = v.w;
        }
        __syncthreads();

        #pragma unroll
        for (int kk = 0; kk < BK; ++kk) {
            float a[8], bv[8];
            #pragma unroll
            for (int i = 0; i < 8; ++i) a[i] = As[kk][ty * 8 + i];
            #pragma unroll
            for (int j = 0; j < 8; ++j) bv[j] = Bs[kk][tx * 8 + j];
            #pragma unroll
            for (int i = 0; i < 8; ++i)
                #pragma unroll
                for (int j = 0; j < 8; ++j)
                    acc[i][j] += a[i] * bv[j];
        }
        __syncthreads();
    }

    // Epilogue: add bias, write proj (chunk-local row-major [Mc][NN])
    #pragma unroll
    for (int i = 0; i < 8; ++i) {
        int r = row0 + ty * 8 + i;
        #pragma unroll
        for (int j = 0; j < 8; j += 4) {
            int o = col0 + tx * 8 + j;
            float4 v;
            v.x = acc[i][j + 0] + bias[o + 0];
            v.y = acc[i][j + 1] + bias[o + 1];
            v.z = acc[i][j + 2] + bias[o + 2];
            v.w = acc[i][j + 3] + bias[o + 3];
            *(float4*)(proj + (size_t)r * NN + o) = v;
        }
    }
}

// ---------------------------------------------------------------------------
// Phase 2: sequential scan over the chunk's Tc steps.
// One thread per (b,d) element: 16384 threads = 256 blocks x 64.
// s' = sig(z0)*s + sig(z1)*tanh(z2)
// h' = sig(z3)*h + sig(z4)*tanh(z5 + s')
// ---------------------------------------------------------------------------
__global__ __launch_bounds__(64) void scan_chunk(
    const float* __restrict__ proj, // [Tc*B, NN] chunk-local
    const float* __restrict__ h0,   // [B, D]
    const float* __restrict__ s0,   // [B, D]
    float* __restrict__ outH,       // [B, T, D]
    float* __restrict__ outS,       // [B, D]
    int t0, int Tc)
{
    const int gid = blockIdx.x * 64 + threadIdx.x;   // 0..16383
    const int b   = gid >> 9;                        // /D
    const int d   = gid & 511;                       // %D

    float h, s;
    if (t0 == 0) {
        h = h0[gid];
        s = s0[gid];
    } else {
        h = outH[((size_t)b * TT + (t0 - 1)) * DD + d];
        s = outS[gid];
    }

    const float* p = proj + d;
    float z[6];
    {
        size_t base = (size_t)b * NN;
        #pragma unroll
        for (int k = 0; k < 6; ++k) z[k] = p[base + k * DD];
    }

    for (int tl = 0; tl < Tc; ++tl) {
        float zn[6];
        if (tl + 1 < Tc) {
            size_t base = (size_t)((tl + 1) * BB + b) * NN;
            #pragma unroll
            for (int k = 0; k < 6; ++k) zn[k] = p[base + k * DD];
        }

        float sg0 = 1.f / (1.f + expf(-z[0]));
        float sg1 = 1.f / (1.f + expf(-z[1]));
        float sg3 = 1.f / (1.f + expf(-z[3]));
        float sg4 = 1.f / (1.f + expf(-z[4]));
        s = sg0 * s + sg1 * tanhf(z[2]);
        h = sg3 * h + sg4 * tanhf(z[5] + s);

        outH[((size_t)b * TT + (t0 + tl)) * DD + d] = h;

        #pragma unroll
        for (int k = 0; k < 6; ++k) z[k] = zn[k];
    }

    outS[gid] = s;
}

// ---------------------------------------------------------------------------
// Host launcher. Chunk T so proj fits in ws (and stays LLC-resident).
// ---------------------------------------------------------------------------
extern "C" void kernel_launch(void* const* d_in, const int* in_sizes, int n_in,
                              void* d_out, int out_size, void* d_ws, size_t ws_size,
                              hipStream_t stream) {
    const float* x    = (const float*)d_in[0];
    const float* h0   = (const float*)d_in[1];
    const float* s0   = (const float*)d_in[2];
    const float* W    = (const float*)d_in[3];
    const float* bias = (const float*)d_in[4];

    float* outH = (float*)d_out;
    float* outS = outH + (size_t)BB * TT * DD;
    float* proj = (float*)d_ws;

    // bytes per time step of proj: B * NN * 4 = 393216
    const size_t bytes_per_t = (size_t)BB * NN * sizeof(float);
    int TcMax = (int)(ws_size / bytes_per_t);
    if (TcMax > 512) TcMax = 512;    // keep chunk ~200MB (LLC-resident)
    TcMax &= ~3;                     // Mc = Tc*32 must be a multiple of BM=128
    if (TcMax < 4) TcMax = 4;        // minimum viable chunk

    for (int t0 = 0; t0 < TT; t0 += TcMax) {
        int Tc = TT - t0;
        if (Tc > TcMax) Tc = TcMax;
        int Mc = Tc * BB;

        dim3 ggrid(NN / BN, Mc / BM);
        gemm_proj<<<ggrid, 256, 0, stream>>>(x, W, bias, proj, t0);

        scan_chunk<<<(BB * DD) / 64, 64, 0, stream>>>(proj, h0, s0, outH, outS, t0, Tc);
    }
}

// Round 2
// 738.374 us; speedup vs baseline: 5.0259x; 5.0259x over previous
//
#include <hip/hip_runtime.h>
#include <hip/hip_bf16.h>
#include <cstddef>
#include <cstdint>

#define BB   32
#define TT   2048
#define DIN  512
#define DD   512
#define NN   3072
#define PROJW 4096   // padded proj row: col = d*8 + k (k=0..5 used, 6,7 pad)
#define PF   8       // scan prefetch depth (steps)

typedef __attribute__((ext_vector_type(4))) float f32x4;
typedef __attribute__((ext_vector_type(8))) short s16x8;

// ---------------------------------------------------------------------------
// helpers
// ---------------------------------------------------------------------------
__device__ __forceinline__ void gl2lds16(const void* g, void* l) {
    __builtin_amdgcn_global_load_lds(
        (const __attribute__((address_space(1))) unsigned*)g,
        (__attribute__((address_space(3))) unsigned*)l, 16, 0, 0);
}

__device__ __forceinline__ unsigned short bfr(float f) {   // f32 -> bf16 RNE
    unsigned u = __float_as_uint(f);
    u += 0x7fffu + ((u >> 16) & 1u);
    return (unsigned short)(u >> 16);
}

__device__ __forceinline__ float blo(unsigned u) { return __uint_as_float(u << 16); }
__device__ __forceinline__ float bhi(unsigned u) { return __uint_as_float(u & 0xffff0000u); }

__device__ __forceinline__ float fsig(float x) {
    return __builtin_amdgcn_rcpf(1.f + __builtin_amdgcn_exp2f(x * -1.44269504f));
}
__device__ __forceinline__ float ftanh(float x) {
    // tanh(x) = 1 - 2/(1+e^{2x}); exp2 arg = 2x*log2(e)
    return 1.f - 2.f * __builtin_amdgcn_rcpf(1.f + __builtin_amdgcn_exp2f(x * 2.88539008f));
}

// ---------------------------------------------------------------------------
// convert x [B][T][DIN] f32 -> x2 [(t*32+b)][DIN] bf16   (GEMM row = t*B+b)
// ---------------------------------------------------------------------------
__global__ __launch_bounds__(256) void convert_x(
    const float* __restrict__ x, unsigned short* __restrict__ x2)
{
    const int total4 = BB * TT * DIN / 4;   // 8388608 float4s
    for (int idx = blockIdx.x * 256 + threadIdx.x; idx < total4;
         idx += gridDim.x * 256) {
        int e = idx * 4;
        int b = e >> 20;            // /(T*DIN)
        int t = (e >> 9) & 2047;    // /DIN % T
        int i = e & 511;            // %DIN  (multiple of 4)
        float4 v = *(const float4*)(x + (size_t)e);
        ushort4 o;
        o.x = bfr(v.x); o.y = bfr(v.y); o.z = bfr(v.z); o.w = bfr(v.w);
        *(ushort4*)(x2 + ((size_t)((t << 5) | b) << 9) + i) = o;
    }
}

// ---------------------------------------------------------------------------
// convert W [NN][DIN] f32 -> W2 [NN][DIN] bf16 with ROW PERMUTATION:
// W2 row c corresponds to gate-interleaved output col c = d*6+k, i.e.
// original W row o = k*512 + d. bias permuted likewise.
// ---------------------------------------------------------------------------
__global__ __launch_bounds__(128) void convert_w(
    const float* __restrict__ W, const float* __restrict__ bias,
    unsigned short* __restrict__ W2, float* __restrict__ bias2)
{
    int c = blockIdx.x;            // 0..3071, = d*6+k
    int d = c / 6, k = c - d * 6;
    int o = (k << 9) + d;
    const float* src = W + (size_t)o * DIN;
    unsigned short* dst = W2 + (size_t)c * DIN;
    int i = threadIdx.x * 4;
    float4 v = *(const float4*)(src + i);
    ushort4 u;
    u.x = bfr(v.x); u.y = bfr(v.y); u.z = bfr(v.z); u.w = bfr(v.w);
    *(ushort4*)(dst + i) = u;
    if (threadIdx.x == 0) bias2[c] = bias[o];
}

// ---------------------------------------------------------------------------
// bf16 MFMA GEMM (m97 structure): proj_tile = x2_tile * W2_tile^T + bias
// 128x128 tile, BK=64, 4 waves (2x2), 16x16x32 MFMA, global_load_lds width 16.
// GEMM col c = d*6+k (W2 pre-permuted); storage col = d*8+k = c + 2*(c/6).
// ---------------------------------------------------------------------------
__global__ __launch_bounds__(256) void gemm_proj(
    const unsigned short* __restrict__ x2,    // [T*32][512]
    const unsigned short* __restrict__ W2,    // [3072][512]
    const float* __restrict__ bias2,          // [3072]
    unsigned short* __restrict__ proj,        // [Mc][PROJW]
    int t0)
{
    __shared__ unsigned short As[128][64];
    __shared__ unsigned short Bs[128][64];

    const int tid  = threadIdx.x;
    const int lane = tid & 63;
    const int w    = tid >> 6;
    const int wr   = w >> 1, wc = w & 1;
    const int lr   = lane & 15, lq = lane >> 4;

    const int row0 = blockIdx.y * 128;        // chunk-local proj row
    const int col0 = blockIdx.x * 128;
    const size_t growA = (size_t)t0 * BB + row0;   // global x2 row

    f32x4 acc[4][4] = {};

    for (int k0 = 0; k0 < DIN; k0 += 64) {
        #pragma unroll
        for (int i = 0; i < 4; ++i) {
            int c  = tid + i * 256;           // 16B chunk id, 0..1023
            int r  = c >> 3;
            int kc = (c & 7) * 8;
            gl2lds16(x2 + (growA + r) * DIN + k0 + kc, &As[r][kc]);
            gl2lds16(W2 + (size_t)(col0 + r) * DIN + k0 + kc, &Bs[r][kc]);
        }
        __syncthreads();

        #pragma unroll
        for (int kk = 0; kk < 64; kk += 32) {
            s16x8 av[4], bv[4];
            #pragma unroll
            for (int i = 0; i < 4; ++i)
                av[i] = *(const s16x8*)&As[wr * 64 + i * 16 + lr][kk + lq * 8];
            #pragma unroll
            for (int j = 0; j < 4; ++j)
                bv[j] = *(const s16x8*)&Bs[wc * 64 + j * 16 + lr][kk + lq * 8];
            #pragma unroll
            for (int i = 0; i < 4; ++i)
                #pragma unroll
                for (int j = 0; j < 4; ++j)
                    acc[i][j] = __builtin_amdgcn_mfma_f32_16x16x32_bf16(
                        av[i], bv[j], acc[i][j], 0, 0, 0);
        }
        __syncthreads();
    }

    // epilogue: bias + bf16 store to padded gate-interleaved layout
    #pragma unroll
    for (int j = 0; j < 4; ++j) {
        int col  = col0 + wc * 64 + j * 16 + lr;          // 0..3071
        int dcol = (int)(((unsigned)col * 43691u) >> 18); // col/6 exact
        int scol = col + 2 * dcol;                        // d*8+k
        float bc = bias2[col];
        #pragma unroll
        for (int i = 0; i < 4; ++i) {
            int rbase = row0 + wr * 64 + i * 16 + lq * 4;
            #pragma unroll
            for (int r = 0; r < 4; ++r) {
                proj[(size_t)(rbase + r) * PROJW + scol] = bfr(acc[i][j][r] + bc);
            }
        }
    }
}

// ---------------------------------------------------------------------------
// Scan: one thread per (b,d), 8-step register prefetch, one dwordx4 per step.
// ---------------------------------------------------------------------------
__global__ __launch_bounds__(64) void scan_chunk(
    const unsigned short* __restrict__ proj,  // [Tc*32][PROJW]
    const float* __restrict__ h0, const float* __restrict__ s0,
    float* __restrict__ outH, float* __restrict__ outS,
    int t0, int Tc)
{
    const int gid = blockIdx.x * 64 + threadIdx.x;   // 0..16383
    const int b   = gid >> 9;
    const int d   = gid & 511;

    float h, s;
    if (t0 == 0) { h = h0[gid]; s = s0[gid]; }
    else {
        h = outH[((size_t)b * TT + (t0 - 1)) * DD + d];
        s = outS[gid];
    }

    const unsigned short* pbase = proj + (size_t)b * PROJW + d * 8;
    const size_t tstride = (size_t)BB * PROJW;       // elements per step
    float* oH = outH + ((size_t)b * TT + t0) * DD + d;

    uint4 bufA[PF], bufB[PF];

    #pragma unroll
    for (int u = 0; u < PF; ++u)
        bufA[u] = *(const uint4*)(pbase + (size_t)u * tstride);

    for (int tb = 0; tb < Tc; tb += 2 * PF) {
        #pragma unroll
        for (int u = 0; u < PF; ++u) {
            int t = tb + PF + u; if (t > Tc - 1) t = Tc - 1;
            bufB[u] = *(const uint4*)(pbase + (size_t)t * tstride);
        }
        #pragma unroll
        for (int u = 0; u < PF; ++u) {
            uint4 U = bufA[u];
            float z0 = blo(U.x), z1 = bhi(U.x);
            float z2 = blo(U.y), z3 = bhi(U.y);
            float z4 = blo(U.z), z5 = bhi(U.z);
            s = fsig(z0) * s + fsig(z1) * ftanh(z2);
            h = fsig(z3) * h + fsig(z4) * ftanh(z5 + s);
            oH[(size_t)(tb + u) * DD] = h;
        }
        #pragma unroll
        for (int u = 0; u < PF; ++u) {
            int t = tb + 2 * PF + u; if (t > Tc - 1) t = Tc - 1;
            bufA[u] = *(const uint4*)(pbase + (size_t)t * tstride);
        }
        #pragma unroll
        for (int u = 0; u < PF; ++u) {
            uint4 U = bufB[u];
            float z0 = blo(U.x), z1 = bhi(U.x);
            float z2 = blo(U.y), z3 = bhi(U.y);
            float z4 = blo(U.z), z5 = bhi(U.z);
            s = fsig(z0) * s + fsig(z1) * ftanh(z2);
            h = fsig(z3) * h + fsig(z4) * ftanh(z5 + s);
            oH[(size_t)(tb + PF + u) * DD] = h;
        }
    }

    outS[gid] = s;
}

// ---------------------------------------------------------------------------
extern "C" void kernel_launch(void* const* d_in, const int* in_sizes, int n_in,
                              void* d_out, int out_size, void* d_ws, size_t ws_size,
                              hipStream_t stream) {
    const float* x    = (const float*)d_in[0];
    const float* h0   = (const float*)d_in[1];
    const float* s0   = (const float*)d_in[2];
    const float* W    = (const float*)d_in[3];
    const float* bias = (const float*)d_in[4];

    float* outH = (float*)d_out;
    float* outS = outH + (size_t)BB * TT * DD;

    char* ws = (char*)d_ws;
    const size_t x2_bytes = (size_t)BB * TT * DIN * 2;       // 64 MB
    const size_t w2_bytes = (size_t)NN * DIN * 2;            // 3 MB
    const size_t b2_bytes = (size_t)NN * 4;
    unsigned short* x2    = (unsigned short*)ws;
    unsigned short* W2    = (unsigned short*)(ws + x2_bytes);
    float*          bias2 = (float*)(ws + x2_bytes + w2_bytes);
    unsigned short* proj  = (unsigned short*)(ws + x2_bytes + w2_bytes + b2_bytes);

    const size_t fixed = x2_bytes + w2_bytes + b2_bytes;
    const size_t per_t = (size_t)BB * PROJW * 2;             // 262144 B
    int TcMax = (int)((ws_size > fixed ? ws_size - fixed : 0) / per_t);
    if (TcMax > 512) TcMax = 512;   // keep proj chunk L3-resident
    TcMax &= ~15;                   // multiple of 2*PF (and of 4 for GEMM grid)
    if (TcMax < 16) TcMax = 16;

    convert_x<<<2048, 256, 0, stream>>>(x, x2);
    convert_w<<<NN, 128, 0, stream>>>(W, bias, W2, bias2);

    for (int t0 = 0; t0 < TT; t0 += TcMax) {
        int Tc = TT - t0;
        if (Tc > TcMax) Tc = TcMax;
        dim3 ggrid(NN / 128, Tc * BB / 128);
        gemm_proj<<<ggrid, 256, 0, stream>>>(x2, W2, bias2, proj, t0);
        scan_chunk<<<(BB * DD) / 64, 64, 0, stream>>>(proj, h0, s0, outH, outS, t0, Tc);
    }
}